// Round 1
// baseline (378.694 us; speedup 1.0000x reference)
//
#include <hip/hip_runtime.h>
#include <hip/hip_bf16.h>

#define N_NODES 1048576
#define H 128
#define B_SESS 4096

typedef __attribute__((ext_vector_type(8))) short bf16x8;
typedef __attribute__((ext_vector_type(4))) float f32x4;

__device__ inline unsigned short f2bf(float f) {
  unsigned int u = __float_as_uint(f);
  u += 0x7FFFu + ((u >> 16) & 1u);   // round-to-nearest-even
  return (unsigned short)(u >> 16);
}

// ---------------------------------------------------------------- kernel 1
// last index of each segment (batch is sorted, every segment nonempty)
__global__ void k_last(const int* __restrict__ batch, int* __restrict__ last_idx) {
  int i = blockIdx.x * blockDim.x + threadIdx.x;
  if (i < N_NODES) {
    if (i == N_NODES - 1 || batch[i] != batch[i + 1]) last_idx[batch[i]] = i;
  }
}

// ---------------------------------------------------------------- kernel 2
// A_pre[b,h] = v_n[b] . W1[h,:] + b1[h] + b2[h]   (f32, LDS-staged W1)
__global__ void k_apre(const float* __restrict__ x, const int* __restrict__ last_idx,
                       const float* __restrict__ W1, const float* __restrict__ b1,
                       const float* __restrict__ b2, float* __restrict__ A_pre) {
  __shared__ float Wl[128][132];   // pad: 132 -> 16B-aligned rows, low conflicts
  __shared__ float vn[8][128];
  int t = threadIdx.x;
  // stage W1 (16384 f32) via float4
  for (int i = 0; i < 16; ++i) {
    int e = (t + i * 256) * 4;
    int r = e >> 7, c = e & 127;
    float4 v = *reinterpret_cast<const float4*>(W1 + e);
    Wl[r][c] = v.x; Wl[r][c + 1] = v.y; Wl[r][c + 2] = v.z; Wl[r][c + 3] = v.w;
  }
  int b0 = blockIdx.x * 8;
  for (int i = t; i < 8 * 128; i += 256) {
    int s = i >> 7, c = i & 127;
    vn[s][c] = x[(size_t)last_idx[b0 + s] * H + c];
  }
  __syncthreads();
  int h = t & 127, si = t >> 7;
  float bias = b1[h] + b2[h];
  for (int s = si; s < 8; s += 2) {
    float acc = bias;
    #pragma unroll
    for (int k = 0; k < 128; k += 4) {
      float4 w = *reinterpret_cast<const float4*>(&Wl[h][k]);
      acc += vn[s][k] * w.x + vn[s][k + 1] * w.y + vn[s][k + 2] * w.z + vn[s][k + 3] * w.w;
    }
    A_pre[(size_t)(b0 + s) * H + h] = acc;
  }
}

// ---------------------------------------------------------------- kernel 3
// Fused: z = A_pre[batch] + x@W2^T (bf16 MFMA), gate = sigmoid(z),
// alpha = gate.Wq + bq, s_g[b] += alpha * x  (per-segment flush via atomics)
__launch_bounds__(256)
__global__ void k_main(const float* __restrict__ x, const int* __restrict__ batch,
                       const float* __restrict__ W2, const float* __restrict__ Wq,
                       const float* __restrict__ bq, const float* __restrict__ A_pre,
                       float* __restrict__ s_g) {
  __shared__ unsigned short Wl[128][136];  // W2 bf16, +8 pad -> 2-way conflicts only
  __shared__ unsigned short Xl[64][136];   // x tile bf16
  __shared__ float alph[64];
  __shared__ int bseg[65];
  __shared__ float wq[128];
  int t = threadIdx.x;
  int node0 = blockIdx.x * 64;

  // stage W2 -> bf16 LDS
  for (int i = 0; i < 16; ++i) {
    int e = (t + i * 256) * 4;
    int r = e >> 7, c = e & 127;
    float4 v = *reinterpret_cast<const float4*>(W2 + e);
    Wl[r][c] = f2bf(v.x); Wl[r][c + 1] = f2bf(v.y);
    Wl[r][c + 2] = f2bf(v.z); Wl[r][c + 3] = f2bf(v.w);
  }
  // stage x tile -> bf16 LDS (64 rows x 128)
  for (int i = 0; i < 8; ++i) {
    int e = (t + i * 256) * 4;
    int r = e >> 7, c = e & 127;
    float4 v = *reinterpret_cast<const float4*>(x + (size_t)node0 * H + e);
    Xl[r][c] = f2bf(v.x); Xl[r][c + 1] = f2bf(v.y);
    Xl[r][c + 2] = f2bf(v.z); Xl[r][c + 3] = f2bf(v.w);
  }
  if (t < 65) {
    int idx = node0 + t;
    bseg[t] = (idx < N_NODES) ? batch[idx] : -1;
  }
  if (t < 128) wq[t] = Wq[t];
  __syncthreads();

  // ---- phase 1: MFMA z-tiles + alpha
  int w = t >> 6, lane = t & 63;
  int r = lane & 15, ks = lane >> 4;
  f32x4 acc[8];
  #pragma unroll
  for (int nt = 0; nt < 8; ++nt) acc[nt] = (f32x4){0.f, 0.f, 0.f, 0.f};
  #pragma unroll
  for (int k0 = 0; k0 < 128; k0 += 32) {
    bf16x8 a = *reinterpret_cast<const bf16x8*>(&Xl[w * 16 + r][k0 + ks * 8]);
    #pragma unroll
    for (int nt = 0; nt < 8; ++nt) {
      bf16x8 b = *reinterpret_cast<const bf16x8*>(&Wl[nt * 16 + r][k0 + ks * 8]);
      acc[nt] = __builtin_amdgcn_mfma_f32_16x16x32_bf16(a, b, acc[nt], 0, 0, 0);
    }
  }
  float bqv = bq[0];
  #pragma unroll
  for (int j = 0; j < 4; ++j) {
    int lrow = w * 16 + ks * 4 + j;       // local node in tile
    int bidx = bseg[lrow];
    float pa = 0.f;
    #pragma unroll
    for (int nt = 0; nt < 8; ++nt) {
      int col = nt * 16 + r;
      float z = acc[nt][j] + A_pre[(size_t)bidx * H + col];
      float g = 1.0f / (1.0f + __expf(-z));
      pa += g * wq[col];
    }
    pa += __shfl_xor(pa, 1);
    pa += __shfl_xor(pa, 2);
    pa += __shfl_xor(pa, 4);
    pa += __shfl_xor(pa, 8);
    if (r == 0) alph[lrow] = pa + bqv;
  }
  __syncthreads();

  // ---- phase 2: s_g[b,h] += alpha_i * x[i,h]  (x re-read f32: L2 hit)
  int h = t & 127, half = t >> 7;
  int base = half * 32;
  float accum = 0.f;
  for (int n = 0; n < 32; ++n) {
    int ln = base + n;
    float a = alph[ln];
    float xv = x[(size_t)(node0 + ln) * H + h];
    accum += a * xv;
    if (bseg[ln] != bseg[ln + 1]) {
      atomicAdd(&s_g[(size_t)bseg[ln] * H + h], accum);
      accum = 0.f;
    }
  }
  if (accum != 0.f) atomicAdd(&s_g[(size_t)bseg[base + 31] * H + h], accum);
}

// ---------------------------------------------------------------- kernel 4
// s_h[b,h] = b3[h] + concat(v_n[b], s_g[b]) . W3[h,:]   (f32)
__global__ void k_final(const float* __restrict__ x, const int* __restrict__ last_idx,
                        const float* __restrict__ s_g, const float* __restrict__ W3,
                        const float* __restrict__ b3, float* __restrict__ out) {
  __shared__ float Wl[128][132];
  __shared__ float vin[8][256];
  int t = threadIdx.x;
  int b0 = blockIdx.x * 8;
  for (int i = t; i < 8 * 256; i += 256) {
    int s = i >> 8, c = i & 255;
    float v;
    if (c < 128) v = x[(size_t)last_idx[b0 + s] * H + c];
    else         v = s_g[(size_t)(b0 + s) * H + (c - 128)];
    vin[s][c] = v;
  }
  int h = t & 127, si = t >> 7;
  float res[4];
  for (int half = 0; half < 2; ++half) {
    __syncthreads();
    for (int i = 0; i < 16; ++i) {
      int e = (t + i * 256) * 4;
      int r = e >> 7, c = e & 127;
      float4 v = *reinterpret_cast<const float4*>(W3 + (size_t)r * 256 + half * 128 + c);
      Wl[r][c] = v.x; Wl[r][c + 1] = v.y; Wl[r][c + 2] = v.z; Wl[r][c + 3] = v.w;
    }
    __syncthreads();
    #pragma unroll
    for (int sI = 0; sI < 4; ++sI) {
      int s = si + sI * 2;
      float acc = 0.f;
      #pragma unroll
      for (int k = 0; k < 128; k += 4) {
        float4 wv = *reinterpret_cast<const float4*>(&Wl[h][k]);
        acc += vin[s][half * 128 + k] * wv.x + vin[s][half * 128 + k + 1] * wv.y +
               vin[s][half * 128 + k + 2] * wv.z + vin[s][half * 128 + k + 3] * wv.w;
      }
      if (half == 0) res[sI] = acc;
      else out[(size_t)(b0 + s) * H + h] = res[sI] + acc + b3[h];
    }
  }
}

// ----------------------------------------------------------------
extern "C" void kernel_launch(void* const* d_in, const int* in_sizes, int n_in,
                              void* d_out, int out_size, void* d_ws, size_t ws_size,
                              hipStream_t stream) {
  const float* x     = (const float*)d_in[0];
  const int*   batch = (const int*)d_in[1];
  const float* W1    = (const float*)d_in[2];
  const float* b1    = (const float*)d_in[3];
  const float* W2    = (const float*)d_in[4];
  const float* b2    = (const float*)d_in[5];
  const float* Wq    = (const float*)d_in[6];
  const float* bq    = (const float*)d_in[7];
  const float* W3    = (const float*)d_in[8];
  const float* b3    = (const float*)d_in[9];
  float* out = (float*)d_out;

  char* ws = (char*)d_ws;
  int*   last_idx = (int*)ws;                                    // 16 KB
  float* A_pre    = (float*)(ws + 16384);                        // 2 MB
  float* s_g      = (float*)(ws + 16384 + (size_t)B_SESS * H * 4); // 2 MB

  hipMemsetAsync(s_g, 0, (size_t)B_SESS * H * sizeof(float), stream);
  k_last<<<N_NODES / 256, 256, 0, stream>>>(batch, last_idx);
  k_apre<<<B_SESS / 8, 256, 0, stream>>>(x, last_idx, W1, b1, b2, A_pre);
  k_main<<<N_NODES / 64, 256, 0, stream>>>(x, batch, W2, Wq, bq, A_pre, s_g);
  k_final<<<B_SESS / 8, 256, 0, stream>>>(x, last_idx, s_g, W3, b3, out);
}

// Round 2
// 345.327 us; speedup vs baseline: 1.0966x; 1.0966x over previous
//
#include <hip/hip_runtime.h>
#include <hip/hip_bf16.h>

#define N_NODES 1048576
#define H 128
#define B_SESS 4096
#define TILE 128

typedef __attribute__((ext_vector_type(8))) short bf16x8;
typedef __attribute__((ext_vector_type(4))) short bf16x4;
typedef __attribute__((ext_vector_type(4))) float f32x4;

__device__ inline unsigned short f2bf(float f) {
  unsigned int u = __float_as_uint(f);
  u += 0x7FFFu + ((u >> 16) & 1u);   // round-to-nearest-even
  return (unsigned short)(u >> 16);
}

// ---------------------------------------------------------------- kernel 0
// one-shot W2 f32 -> bf16
__global__ void k_w2(const float* __restrict__ W2, unsigned short* __restrict__ W2b) {
  int i = blockIdx.x * 256 + threadIdx.x;     // 16 blocks: 4096 threads x 4 elems
  float4 v = *reinterpret_cast<const float4*>(W2 + (size_t)i * 4);
  bf16x4 o;
  o[0] = (short)f2bf(v.x); o[1] = (short)f2bf(v.y);
  o[2] = (short)f2bf(v.z); o[3] = (short)f2bf(v.w);
  *reinterpret_cast<bf16x4*>(W2b + (size_t)i * 4) = o;
}

// ---------------------------------------------------------------- kernel 1
// last index of each segment (batch is sorted, every segment nonempty)
__global__ void k_last(const int* __restrict__ batch, int* __restrict__ last_idx) {
  int i = blockIdx.x * blockDim.x + threadIdx.x;
  if (i < N_NODES) {
    if (i == N_NODES - 1 || batch[i] != batch[i + 1]) last_idx[batch[i]] = i;
  }
}

// ---------------------------------------------------------------- kernel 2
// A_pre[b,h] = v_n[b] . W1[h,:] + b1[h] + b2[h]   (f32, LDS-staged W1)
__global__ void k_apre(const float* __restrict__ x, const int* __restrict__ last_idx,
                       const float* __restrict__ W1, const float* __restrict__ b1,
                       const float* __restrict__ b2, float* __restrict__ A_pre) {
  __shared__ float Wl[128][132];
  __shared__ float vn[8][128];
  int t = threadIdx.x;
  for (int i = 0; i < 16; ++i) {
    int e = (t + i * 256) * 4;
    int r = e >> 7, c = e & 127;
    float4 v = *reinterpret_cast<const float4*>(W1 + e);
    Wl[r][c] = v.x; Wl[r][c + 1] = v.y; Wl[r][c + 2] = v.z; Wl[r][c + 3] = v.w;
  }
  int b0 = blockIdx.x * 8;
  for (int i = t; i < 8 * 128; i += 256) {
    int s = i >> 7, c = i & 127;
    vn[s][c] = x[(size_t)last_idx[b0 + s] * H + c];
  }
  __syncthreads();
  int h = t & 127, si = t >> 7;
  float bias = b1[h] + b2[h];
  for (int s = si; s < 8; s += 2) {
    float acc = bias;
    #pragma unroll
    for (int k = 0; k < 128; k += 4) {
      float4 w = *reinterpret_cast<const float4*>(&Wl[h][k]);
      acc += vn[s][k] * w.x + vn[s][k + 1] * w.y + vn[s][k + 2] * w.z + vn[s][k + 3] * w.w;
    }
    A_pre[(size_t)(b0 + s) * H + h] = acc;
  }
}

// ---------------------------------------------------------------- kernel 3
// Fused: z = A_pre[batch] + x@W2^T (bf16 MFMA, A-frags direct from global),
// gate = sigmoid(z), alpha = gate.Wq + bq, s_g[b] += alpha * x
__launch_bounds__(512)
__global__ void k_main(const float* __restrict__ x, const int* __restrict__ batch,
                       const unsigned short* __restrict__ W2b, const float* __restrict__ Wq,
                       const float* __restrict__ bq, const float* __restrict__ A_pre,
                       float* __restrict__ s_g) {
  __shared__ unsigned short Wl[128][136];  // bf16 W2; row stride 272B = 17*16 (16B-aligned)
  __shared__ float alph[TILE];
  __shared__ int bseg[TILE + 1];
  __shared__ float wq[128];
  int t = threadIdx.x;
  int node0 = blockIdx.x * TILE;

  // stage pre-converted W2 bf16 (32KB) via 16B copies
  #pragma unroll
  for (int i = 0; i < 4; ++i) {
    int e = (t + i * 512) * 8;
    int r = e >> 7, c = e & 127;
    *reinterpret_cast<bf16x8*>(&Wl[r][c]) = *reinterpret_cast<const bf16x8*>(W2b + e);
  }
  if (t <= TILE) {
    int idx = node0 + t;
    bseg[t] = (idx < N_NODES) ? batch[idx] : -1;
  }
  if (t < 128) wq[t] = Wq[t];
  __syncthreads();

  // ---- phase 1: MFMA z-tiles + alpha (A-fragments direct from global x)
  int w = t >> 6, lane = t & 63, r = lane & 15, ks = lane >> 4;
  const float* xrow = x + (size_t)(node0 + w * 16 + r) * H;
  f32x4 acc[8];
  #pragma unroll
  for (int nt = 0; nt < 8; ++nt) acc[nt] = (f32x4){0.f, 0.f, 0.f, 0.f};
  #pragma unroll
  for (int k0 = 0; k0 < 128; k0 += 32) {
    float4 f0 = *reinterpret_cast<const float4*>(xrow + k0 + ks * 8);
    float4 f1 = *reinterpret_cast<const float4*>(xrow + k0 + ks * 8 + 4);
    bf16x8 a;
    a[0] = (short)f2bf(f0.x); a[1] = (short)f2bf(f0.y);
    a[2] = (short)f2bf(f0.z); a[3] = (short)f2bf(f0.w);
    a[4] = (short)f2bf(f1.x); a[5] = (short)f2bf(f1.y);
    a[6] = (short)f2bf(f1.z); a[7] = (short)f2bf(f1.w);
    #pragma unroll
    for (int nt = 0; nt < 8; ++nt) {
      bf16x8 b = *reinterpret_cast<const bf16x8*>(&Wl[nt * 16 + r][k0 + ks * 8]);
      acc[nt] = __builtin_amdgcn_mfma_f32_16x16x32_bf16(a, b, acc[nt], 0, 0, 0);
    }
  }
  float bqv = bq[0];
  #pragma unroll
  for (int j = 0; j < 4; ++j) {
    int lrow = w * 16 + ks * 4 + j;
    const float* ap = A_pre + (size_t)bseg[lrow] * H;
    float pa = 0.f;
    #pragma unroll
    for (int nt = 0; nt < 8; ++nt) {
      float z = acc[nt][j] + ap[nt * 16 + r];
      float g = 1.0f / (1.0f + __expf(-z));
      pa += g * wq[nt * 16 + r];
    }
    pa += __shfl_xor(pa, 1);
    pa += __shfl_xor(pa, 2);
    pa += __shfl_xor(pa, 4);
    pa += __shfl_xor(pa, 8);
    if (r == 0) alph[lrow] = pa + bqv;
  }
  __syncthreads();

  // ---- phase 2: s_g[b,h] += alpha_i * x[i,h]  (x re-read f32: L2 hit)
  int h = t & 127, grp = t >> 7;            // 4 groups x 32 nodes
  int base = grp * 32;
  const float* xp = x + (size_t)(node0 + base) * H + h;
  float accum = 0.f;
  for (int n = 0; n < 32; ++n) {
    int ln = base + n;
    accum += alph[ln] * xp[(size_t)n * H];
    if (bseg[ln] != bseg[ln + 1]) {
      atomicAdd(&s_g[(size_t)bseg[ln] * H + h], accum);
      accum = 0.f;
    }
  }
  if (accum != 0.f) atomicAdd(&s_g[(size_t)bseg[base + 31] * H + h], accum);
}

// ---------------------------------------------------------------- kernel 4
// s_h[b,h] = b3[h] + concat(v_n[b], s_g[b]) . W3[h,:]   (f32)
__global__ void k_final(const float* __restrict__ x, const int* __restrict__ last_idx,
                        const float* __restrict__ s_g, const float* __restrict__ W3,
                        const float* __restrict__ b3, float* __restrict__ out) {
  __shared__ float Wl[128][132];
  __shared__ float vin[8][256];
  int t = threadIdx.x;
  int b0 = blockIdx.x * 8;
  for (int i = t; i < 8 * 256; i += 256) {
    int s = i >> 8, c = i & 255;
    float v;
    if (c < 128) v = x[(size_t)last_idx[b0 + s] * H + c];
    else         v = s_g[(size_t)(b0 + s) * H + (c - 128)];
    vin[s][c] = v;
  }
  int h = t & 127, si = t >> 7;
  float res[4];
  for (int half = 0; half < 2; ++half) {
    __syncthreads();
    for (int i = 0; i < 16; ++i) {
      int e = (t + i * 256) * 4;
      int r = e >> 7, c = e & 127;
      float4 v = *reinterpret_cast<const float4*>(W3 + (size_t)r * 256 + half * 128 + c);
      Wl[r][c] = v.x; Wl[r][c + 1] = v.y; Wl[r][c + 2] = v.z; Wl[r][c + 3] = v.w;
    }
    __syncthreads();
    #pragma unroll
    for (int sI = 0; sI < 4; ++sI) {
      int s = si + sI * 2;
      float acc = 0.f;
      #pragma unroll
      for (int k = 0; k < 128; k += 4) {
        float4 wv = *reinterpret_cast<const float4*>(&Wl[h][k]);
        acc += vin[s][half * 128 + k] * wv.x + vin[s][half * 128 + k + 1] * wv.y +
               vin[s][half * 128 + k + 2] * wv.z + vin[s][half * 128 + k + 3] * wv.w;
      }
      if (half == 0) res[sI] = acc;
      else out[(size_t)(b0 + s) * H + h] = res[sI] + acc + b3[h];
    }
  }
}

// ----------------------------------------------------------------
extern "C" void kernel_launch(void* const* d_in, const int* in_sizes, int n_in,
                              void* d_out, int out_size, void* d_ws, size_t ws_size,
                              hipStream_t stream) {
  const float* x     = (const float*)d_in[0];
  const int*   batch = (const int*)d_in[1];
  const float* W1    = (const float*)d_in[2];
  const float* b1    = (const float*)d_in[3];
  const float* W2    = (const float*)d_in[4];
  const float* b2    = (const float*)d_in[5];
  const float* Wq    = (const float*)d_in[6];
  const float* bq    = (const float*)d_in[7];
  const float* W3    = (const float*)d_in[8];
  const float* b3    = (const float*)d_in[9];
  float* out = (float*)d_out;

  char* ws = (char*)d_ws;
  int*            last_idx = (int*)ws;                               // 16 KB
  float*          A_pre    = (float*)(ws + 16384);                   // 2 MB
  float*          s_g      = (float*)(ws + 16384 + 2097152);         // 2 MB
  unsigned short* W2b      = (unsigned short*)(ws + 16384 + 2 * 2097152); // 32 KB

  hipMemsetAsync(s_g, 0, (size_t)B_SESS * H * sizeof(float), stream);
  k_w2<<<16, 256, 0, stream>>>(W2, W2b);
  k_last<<<N_NODES / 256, 256, 0, stream>>>(batch, last_idx);
  k_apre<<<B_SESS / 8, 256, 0, stream>>>(x, last_idx, W1, b1, b2, A_pre);
  k_main<<<N_NODES / TILE, 512, 0, stream>>>(x, batch, W2b, Wq, bq, A_pre, s_g);
  k_final<<<B_SESS / 8, 256, 0, stream>>>(x, last_idx, s_g, W3, b3, out);
}

// Round 3
// 232.410 us; speedup vs baseline: 1.6294x; 1.4859x over previous
//
#include <hip/hip_runtime.h>
#include <hip/hip_bf16.h>

#define N_NODES 1048576
#define H 128
#define B_SESS 4096
#define TILE 128

typedef __attribute__((ext_vector_type(8))) short bf16x8;
typedef __attribute__((ext_vector_type(4))) short bf16x4;
typedef __attribute__((ext_vector_type(4))) float f32x4;

__device__ inline unsigned short f2bf(float f) {
  unsigned int u = __float_as_uint(f);
  u += 0x7FFFu + ((u >> 16) & 1u);   // round-to-nearest-even
  return (unsigned short)(u >> 16);
}

// ---------------------------------------------------------------- kernel 0
// one-shot W2 f32 -> bf16
__global__ void k_w2(const float* __restrict__ W2, unsigned short* __restrict__ W2b) {
  int i = blockIdx.x * 256 + threadIdx.x;
  float4 v = *reinterpret_cast<const float4*>(W2 + (size_t)i * 4);
  bf16x4 o;
  o[0] = (short)f2bf(v.x); o[1] = (short)f2bf(v.y);
  o[2] = (short)f2bf(v.z); o[3] = (short)f2bf(v.w);
  *reinterpret_cast<bf16x4*>(W2b + (size_t)i * 4) = o;
}

// ---------------------------------------------------------------- kernel 1
// last index of each segment (batch is sorted, every segment nonempty)
__global__ void k_last(const int* __restrict__ batch, int* __restrict__ last_idx) {
  int i = blockIdx.x * blockDim.x + threadIdx.x;
  if (i < N_NODES) {
    if (i == N_NODES - 1 || batch[i] != batch[i + 1]) last_idx[batch[i]] = i;
  }
}

// ---------------------------------------------------------------- kernel 2
// A_pre[b,h] = v_n[b] . W1[h,:] + b1[h] + b2[h]   (f32, LDS-staged W1)
__global__ void k_apre(const float* __restrict__ x, const int* __restrict__ last_idx,
                       const float* __restrict__ W1, const float* __restrict__ b1,
                       const float* __restrict__ b2, float* __restrict__ A_pre) {
  __shared__ float Wl[128][132];
  __shared__ float vn[8][128];
  int t = threadIdx.x;
  for (int i = 0; i < 16; ++i) {
    int e = (t + i * 256) * 4;
    int r = e >> 7, c = e & 127;
    float4 v = *reinterpret_cast<const float4*>(W1 + e);
    Wl[r][c] = v.x; Wl[r][c + 1] = v.y; Wl[r][c + 2] = v.z; Wl[r][c + 3] = v.w;
  }
  int b0 = blockIdx.x * 8;
  for (int i = t; i < 8 * 128; i += 256) {
    int s = i >> 7, c = i & 127;
    vn[s][c] = x[(size_t)last_idx[b0 + s] * H + c];
  }
  __syncthreads();
  int h = t & 127, si = t >> 7;
  float bias = b1[h] + b2[h];
  for (int s = si; s < 8; s += 2) {
    float acc = bias;
    #pragma unroll
    for (int k = 0; k < 128; k += 4) {
      float4 w = *reinterpret_cast<const float4*>(&Wl[h][k]);
      acc += vn[s][k] * w.x + vn[s][k + 1] * w.y + vn[s][k + 2] * w.z + vn[s][k + 3] * w.w;
    }
    A_pre[(size_t)(b0 + s) * H + h] = acc;
  }
}

// ---------------------------------------------------------------- kernel 3
// Fused: z = A_pre[batch] + x@W2^T (bf16 MFMA, x staged coalesced -> bf16 LDS),
// gate = sigmoid(z), alpha = gate.Wq + bq, s_g[b] += alpha * x (x from LDS)
__launch_bounds__(512)
__global__ void k_main(const float* __restrict__ x, const int* __restrict__ batch,
                       const unsigned short* __restrict__ W2b, const float* __restrict__ Wq,
                       const float* __restrict__ bq, const float* __restrict__ A_pre,
                       float* __restrict__ s_g) {
  __shared__ unsigned short Wl[128][136];  // bf16 W2; row stride 272B (16B-aligned)
  __shared__ unsigned short Xl[TILE][136]; // bf16 x tile
  __shared__ float alph[TILE];
  __shared__ int bseg[TILE + 1];
  __shared__ float wq[128];
  int t = threadIdx.x;
  int node0 = blockIdx.x * TILE;

  // stage x tile: coalesced float4 reads -> bf16 -> LDS (128 rows x 128 cols)
  #pragma unroll
  for (int i = 0; i < 8; ++i) {
    int e = (t + i * 512) * 4;                 // elem index in 128x128 tile
    int r = e >> 7, c = e & 127;
    float4 v = *reinterpret_cast<const float4*>(x + (size_t)node0 * H + e);
    bf16x4 o;
    o[0] = (short)f2bf(v.x); o[1] = (short)f2bf(v.y);
    o[2] = (short)f2bf(v.z); o[3] = (short)f2bf(v.w);
    *reinterpret_cast<bf16x4*>(&Xl[r][c]) = o;
  }
  // stage pre-converted W2 bf16 (32KB) via 16B copies
  #pragma unroll
  for (int i = 0; i < 4; ++i) {
    int e = (t + i * 512) * 8;
    int r = e >> 7, c = e & 127;
    *reinterpret_cast<bf16x8*>(&Wl[r][c]) = *reinterpret_cast<const bf16x8*>(W2b + e);
  }
  if (t <= TILE) {
    int idx = node0 + t;
    bseg[t] = (idx < N_NODES) ? batch[idx] : -1;
  }
  if (t < 128) wq[t] = Wq[t];
  __syncthreads();

  // ---- phase 1: MFMA z-tiles + alpha (A- and B-frags from LDS)
  int w = t >> 6, lane = t & 63, r = lane & 15, ks = lane >> 4;
  f32x4 acc[8];
  #pragma unroll
  for (int nt = 0; nt < 8; ++nt) acc[nt] = (f32x4){0.f, 0.f, 0.f, 0.f};
  #pragma unroll
  for (int k0 = 0; k0 < 128; k0 += 32) {
    bf16x8 a = *reinterpret_cast<const bf16x8*>(&Xl[w * 16 + r][k0 + ks * 8]);
    #pragma unroll
    for (int nt = 0; nt < 8; ++nt) {
      bf16x8 b = *reinterpret_cast<const bf16x8*>(&Wl[nt * 16 + r][k0 + ks * 8]);
      acc[nt] = __builtin_amdgcn_mfma_f32_16x16x32_bf16(a, b, acc[nt], 0, 0, 0);
    }
  }
  float bqv = bq[0];
  #pragma unroll
  for (int j = 0; j < 4; ++j) {
    int lrow = w * 16 + ks * 4 + j;
    const float* ap = A_pre + (size_t)bseg[lrow] * H;
    float pa = 0.f;
    #pragma unroll
    for (int nt = 0; nt < 8; ++nt) {
      float z = acc[nt][j] + ap[nt * 16 + r];
      float g = 1.0f / (1.0f + __expf(-z));
      pa += g * wq[nt * 16 + r];
    }
    pa += __shfl_xor(pa, 1);
    pa += __shfl_xor(pa, 2);
    pa += __shfl_xor(pa, 4);
    pa += __shfl_xor(pa, 8);
    if (r == 0) alph[lrow] = pa + bqv;
  }
  __syncthreads();

  // ---- phase 2: s_g[b,h] += alpha_i * x[i,h]   (x from LDS bf16)
  int h = t & 127, grp = t >> 7;            // 4 groups x 32 nodes
  int base = grp * 32;
  float accum = 0.f;
  #pragma unroll 4
  for (int n = 0; n < 32; ++n) {
    int ln = base + n;
    float xv = __uint_as_float((unsigned int)Xl[ln][h] << 16);
    accum += alph[ln] * xv;
    if (bseg[ln] != bseg[ln + 1]) {
      atomicAdd(&s_g[(size_t)bseg[ln] * H + h], accum);
      accum = 0.f;
    }
  }
  if (accum != 0.f) atomicAdd(&s_g[(size_t)bseg[base + 31] * H + h], accum);
}

// ---------------------------------------------------------------- kernel 4
// s_h[b,h] = b3[h] + concat(v_n[b], s_g[b]) . W3[h,:]   (f32)
__global__ void k_final(const float* __restrict__ x, const int* __restrict__ last_idx,
                        const float* __restrict__ s_g, const float* __restrict__ W3,
                        const float* __restrict__ b3, float* __restrict__ out) {
  __shared__ float Wl[128][132];
  __shared__ float vin[8][256];
  int t = threadIdx.x;
  int b0 = blockIdx.x * 8;
  for (int i = t; i < 8 * 256; i += 256) {
    int s = i >> 8, c = i & 255;
    float v;
    if (c < 128) v = x[(size_t)last_idx[b0 + s] * H + c];
    else         v = s_g[(size_t)(b0 + s) * H + (c - 128)];
    vin[s][c] = v;
  }
  int h = t & 127, si = t >> 7;
  float res[4];
  for (int half = 0; half < 2; ++half) {
    __syncthreads();
    for (int i = 0; i < 16; ++i) {
      int e = (t + i * 256) * 4;
      int r = e >> 7, c = e & 127;
      float4 v = *reinterpret_cast<const float4*>(W3 + (size_t)r * 256 + half * 128 + c);
      Wl[r][c] = v.x; Wl[r][c + 1] = v.y; Wl[r][c + 2] = v.z; Wl[r][c + 3] = v.w;
    }
    __syncthreads();
    #pragma unroll
    for (int sI = 0; sI < 4; ++sI) {
      int s = si + sI * 2;
      float acc = 0.f;
      #pragma unroll
      for (int k = 0; k < 128; k += 4) {
        float4 wv = *reinterpret_cast<const float4*>(&Wl[h][k]);
        acc += vin[s][half * 128 + k] * wv.x + vin[s][half * 128 + k + 1] * wv.y +
               vin[s][half * 128 + k + 2] * wv.z + vin[s][half * 128 + k + 3] * wv.w;
      }
      if (half == 0) res[sI] = acc;
      else out[(size_t)(b0 + s) * H + h] = res[sI] + acc + b3[h];
    }
  }
}

// ----------------------------------------------------------------
extern "C" void kernel_launch(void* const* d_in, const int* in_sizes, int n_in,
                              void* d_out, int out_size, void* d_ws, size_t ws_size,
                              hipStream_t stream) {
  const float* x     = (const float*)d_in[0];
  const int*   batch = (const int*)d_in[1];
  const float* W1    = (const float*)d_in[2];
  const float* b1    = (const float*)d_in[3];
  const float* W2    = (const float*)d_in[4];
  const float* b2    = (const float*)d_in[5];
  const float* Wq    = (const float*)d_in[6];
  const float* bq    = (const float*)d_in[7];
  const float* W3    = (const float*)d_in[8];
  const float* b3    = (const float*)d_in[9];
  float* out = (float*)d_out;

  char* ws = (char*)d_ws;
  int*            last_idx = (int*)ws;                                    // 16 KB
  float*          A_pre    = (float*)(ws + 16384);                        // 2 MB
  float*          s_g      = (float*)(ws + 16384 + 2097152);              // 2 MB
  unsigned short* W2b      = (unsigned short*)(ws + 16384 + 2 * 2097152); // 32 KB

  hipMemsetAsync(s_g, 0, (size_t)B_SESS * H * sizeof(float), stream);
  k_w2<<<16, 256, 0, stream>>>(W2, W2b);
  k_last<<<N_NODES / 256, 256, 0, stream>>>(batch, last_idx);
  k_apre<<<B_SESS / 8, 256, 0, stream>>>(x, last_idx, W1, b1, b2, A_pre);
  k_main<<<N_NODES / TILE, 512, 0, stream>>>(x, batch, W2b, Wq, bq, A_pre, s_g);
  k_final<<<B_SESS / 8, 256, 0, stream>>>(x, last_idx, s_g, W3, b3, out);
}